// Round 5
// baseline (443.534 us; speedup 1.0000x reference)
//
#include <hip/hip_runtime.h>

// Inputs: M (f32, 2048x4096), params (f32, 4096), kinds (int32, 4096).
// Output: f32, 10240x10240.
// Timing model (R4 post-mortem): harness fixed overhead ~342 us (1.6 GiB ws
// poison 267 + 400 MiB out poison 64 + input restore ~11); our kernels are
// the remaining ~90 us. Floor = 452 MB @ 6.36 TB/s = 71 us.
#define NN 2048              // N_NODES
#define EE 4096              // N_ELEMS
#define WW 10240             // 2*E + N columns
#define TOT_ROWS 10240       // N + 2*E rows

typedef float v4f __attribute__((ext_vector_type(4)));

// ---------------------------------------------------------------------------
// row_kernel: one block per output row; every store is part of a contiguous
// 40 KB (or 32 KB) per-row stream — memset-like access pattern.
//   rows [0,N):      [copy M row | zeros]           (10 v4/thread)
//   rows [N,N+E):    [zeros | I_E] cols [0,2E) only ( 8 v4/thread; -M^T owned
//                                                     by tp_kernel)
//   rows [N+E,2E+N): zeros + z@e + y@(E+e)          (10 v4/thread)
// ---------------------------------------------------------------------------
__global__ __launch_bounds__(256) void row_kernel(
    const float* __restrict__ M,
    const float* __restrict__ params,
    const int*   __restrict__ kinds,
    float*       __restrict__ out)
{
    int row = blockIdx.x;
    int tid = threadIdx.x;
    float* dst = out + (size_t)row * WW;
    const v4f zero = {0.f, 0.f, 0.f, 0.f};

    if (row < NN) {
        const float* src = M + (size_t)row * EE;
        #pragma unroll
        for (int k = 0; k < 4; ++k) {
            int off = (k * 256 + tid) * 4;
            *(v4f*)(dst + off) = *(const v4f*)(src + off);
        }
        #pragma unroll
        for (int k = 4; k < 10; ++k)
            *(v4f*)(dst + (k * 256 + tid) * 4) = zero;
    } else if (row < NN + EE) {
        int e = row - NN;
        int col_y = EE + e;                  // single 1.0 of I_E
        #pragma unroll
        for (int k = 0; k < 8; ++k) {
            int base = (k * 256 + tid) * 4;
            v4f v = zero;
            #pragma unroll
            for (int j = 0; j < 4; ++j)
                if (base + j == col_y) v[j] = 1.0f;
            *(v4f*)(dst + base) = v;
        }
    } else {
        int e = row - (NN + EE);
        float p = params[e];
        int kk = kinds[e];
        bool on = p > 0.0f;
        float z, y;
        if (kk == 0)      { z = -p;             y = 1.0f; }           // R
        else if (kk == 1) { z = 0.0f;           y = 1.0f; }           // IVS
        else if (kk == 2) { z = 1.0f;           y = 0.0f; }           // VC
        else              { z = on ? 0.f : 1.f; y = on ? 1.f : 0.f; } // SW
        int col_z = e, col_y = EE + e;
        #pragma unroll
        for (int k = 0; k < 10; ++k) {
            int base = (k * 256 + tid) * 4;
            v4f v = zero;
            #pragma unroll
            for (int j = 0; j < 4; ++j) {
                if (base + j == col_z) v[j] = z;
                if (base + j == col_y) v[j] = y;
            }
            *(v4f*)(dst + base) = v;
        }
    }
}

// ---------------------------------------------------------------------------
// tp_kernel: out[N+cT+e][2E+rT+j] = -M[rT+j][cT+e], 256(M rows) x 64(M cols)
// tiles = four verified 64x64 sub-tiles (XOR swizzle t[c*64+(r^4*(c&15))],
// round-3 exact). Each output row receives a 1 KB contiguous chunk per block
// (vs 256 B in round 4) — better DRAM page locality for the scattered region.
// M's second read hits L2/L3 (row_kernel just streamed all 33.5 MB of M).
// LDS 64 KB -> 2 blocks/CU; 512 blocks = exactly 2/CU.
// ---------------------------------------------------------------------------
__global__ __launch_bounds__(256) void tp_kernel(
    const float* __restrict__ M,
    float*       __restrict__ out)
{
    __shared__ __align__(16) float t[4][64 * 64];
    int cT = blockIdx.x << 6;    // M col base (output row base)
    int rT = blockIdx.y << 8;    // M row base (output col base)
    int tid = threadIdx.x;
    int r = tid & 15, q = tid >> 4;
    int c0 = r * 4;

    #pragma unroll
    for (int w = 0; w < 4; ++w) {
        #pragma unroll
        for (int it = 0; it < 4; ++it) {
            int lrow = it * 16 + q;          // row within sub-tile
            v4f val = *(const v4f*)(M + (size_t)(rT + w * 64 + lrow) * EE + cT + c0);
            #pragma unroll
            for (int s = 0; s < 4; ++s) {
                int i = (s + (r >> 2)) & 3;  // rotate to spread banks
                int c = c0 + i;
                t[w][c * 64 + (lrow ^ ((c & 15) * 4))] = val[i];
            }
        }
    }
    __syncthreads();

    #pragma unroll
    for (int it = 0; it < 4; ++it) {
        int e  = it * 16 + q;                // output row within tile (M col)
        int j0 = r * 4;
        float* dst = out + (size_t)(NN + cT + e) * WW + 2 * EE + rT + j0;
        #pragma unroll
        for (int w = 0; w < 4; ++w) {        // 4 x 256 B adjacent = 1 KB/row
            v4f v = *(const v4f*)(&t[w][e * 64 + (j0 ^ ((e & 15) * 4))]);
            v4f nv = { -v[0], -v[1], -v[2], -v[3] };
            *(v4f*)(dst + w * 64) = nv;
        }
    }
}

// ---------------------------------------------------------------------------
extern "C" void kernel_launch(void* const* d_in, const int* in_sizes, int n_in,
                              void* d_out, int out_size, void* d_ws, size_t ws_size,
                              hipStream_t stream) {
    const float* M      = (const float*)d_in[0];   // f32, 2048x4096
    const float* params = (const float*)d_in[1];   // f32, 4096
    const int*   kinds  = (const int*)d_in[2];     // int32, 4096
    float*       out    = (float*)d_out;           // f32, 10240x10240

    // row streamer first: writes all streaming regions and warms M into L2/L3
    row_kernel<<<TOT_ROWS, 256, 0, stream>>>(M, params, kinds, out);
    // transpose second: -M^T region, M read likely L2/L3-resident
    tp_kernel<<<dim3(EE / 64, NN / 256), 256, 0, stream>>>(M, out);
}

// Round 6
// 429.167 us; speedup vs baseline: 1.0335x; 1.0335x over previous
//
#include <hip/hip_runtime.h>

// Inputs: M (f32, 2048x4096), params (f32, 4096), kinds (int32, 4096).
// Output: f32, 10240x10240.
// Timing model (R5 post-mortem): fixed harness overhead ~343 us/iter
// (1.6 GiB ws poison 267 + 400 MiB out poison ~65 + M restore ~11).
// Controllable floor: 419 MB write + 33.5 MB read @ 6.36 TB/s ~= 71 us
// -> window floor ~= 414 us. R3/R4/R5 = 437.6/434.2/443.5.
#define NN 2048              // N_NODES
#define EE 4096              // N_ELEMS
#define WW 10240             // 2*E + N columns
#define TOT_ROWS 10240       // N + 2*E rows

typedef float v4f __attribute__((ext_vector_type(4)));

#define TP_BLOCKS 512        // 256(M rows) x 64(M cols) tiles: 8 x 64

__device__ __forceinline__ void nt_store(float* p, v4f v) {
    __builtin_nontemporal_store(v, (v4f*)p);   // streamed, zero-reuse output
}

// Single fused kernel (one launch; R5's two-launch split regressed):
//  blocks [0, 512):    256x64 tile of M -> straight copy (rows [0,N), cols
//                      [0,E)) AND -M^T (rows [N,N+E), cols [2E,W)). M read
//                      exactly once, coalesced. Each output row in the -M^T
//                      region receives a 1 KB contiguous chunk (R5's tile
//                      shape) instead of R4's 256 B. 64 KB LDS -> 2 blk/CU,
//                      512 blocks = exactly 2/CU; dispatched first.
//  blocks [512, ...):  one output ROW per block, pure streaming stores
//                      (memset-like), non-temporal.
// Every output element is written exactly once (out re-poisoned each call).
__global__ __launch_bounds__(256) void coeff_kernel(
    const float* __restrict__ M,
    const float* __restrict__ params,
    const int*   __restrict__ kinds,
    float*       __restrict__ out)
{
    int tid = threadIdx.x;

    if (blockIdx.x < TP_BLOCKS) {
        // XOR-swizzled LDS: t[w][c*64 + (r ^ 4*(c&15))]; scatter <=2-way per
        // bank, float4 reads contiguous (XOR value is 4-aligned). Mapping
        // verified exact in rounds 3-5.
        __shared__ __align__(16) float t[4][64 * 64];
        int cT = (blockIdx.x & 63) << 6;  // M col base (output row base)
        int rT = (blockIdx.x >> 6) << 8;  // M row base (output col base)
        int r = tid & 15, q = tid >> 4;
        int c0 = r * 4;

        #pragma unroll
        for (int w = 0; w < 4; ++w) {
            #pragma unroll
            for (int it = 0; it < 4; ++it) {
                int lrow = it * 16 + q;                    // row in sub-tile
                int grow = rT + w * 64 + lrow;             // global M row
                v4f val = *(const v4f*)(M + (size_t)grow * EE + cT + c0);
                // straight copy block
                nt_store(out + (size_t)grow * WW + cT + c0, val);
                #pragma unroll
                for (int s = 0; s < 4; ++s) {
                    int i = (s + (r >> 2)) & 3;            // bank-spread rotate
                    int c = c0 + i;
                    t[w][c * 64 + (lrow ^ ((c & 15) * 4))] = val[i];
                }
            }
        }
        __syncthreads();

        #pragma unroll
        for (int it = 0; it < 4; ++it) {
            int e  = it * 16 + q;          // output row within tile (M col)
            int j0 = r * 4;
            float* dst = out + (size_t)(NN + cT + e) * WW + 2 * EE + rT + j0;
            #pragma unroll
            for (int w = 0; w < 4; ++w) {  // 4 adjacent 256 B = 1 KB per row
                v4f v = *(const v4f*)(&t[w][e * 64 + (j0 ^ ((e & 15) * 4))]);
                v4f nv = { -v[0], -v[1], -v[2], -v[3] };
                nt_store(dst + w * 64, nv);
            }
        }
    } else {
        int row = blockIdx.x - TP_BLOCKS;     // [0, 10240)
        int tid4 = tid * 4;
        float* dst = out + (size_t)row * WW;
        const v4f zero = {0.f, 0.f, 0.f, 0.f};

        if (row < NN) {
            // kcl rows: cols [0,E) owned by TP tiles; [E,W) zeros.
            #pragma unroll
            for (int k = 4; k < 10; ++k)
                nt_store(dst + k * 1024 + tid4, zero);
        } else if (row < NN + EE) {
            // kvl rows: [0 | I_E] (cols [0,2E); -M^T owned by TP tiles)
            int e = row - NN;
            int col_y = EE + e;
            #pragma unroll
            for (int k = 0; k < 8; ++k) {
                int base = k * 1024 + tid4;
                v4f v = zero;
                #pragma unroll
                for (int j = 0; j < 4; ++j)
                    if (base + j == col_y) v[j] = 1.0f;
                nt_store(dst + base, v);
            }
        } else {
            // elem rows: z at col e, y at col E+e
            int e = row - (NN + EE);
            float p = params[e];
            int kk = kinds[e];
            bool on = p > 0.0f;
            float z, y;
            if (kk == 0)      { z = -p;             y = 1.0f; }           // R
            else if (kk == 1) { z = 0.0f;           y = 1.0f; }           // IVS
            else if (kk == 2) { z = 1.0f;           y = 0.0f; }           // VC
            else              { z = on ? 0.f : 1.f; y = on ? 1.f : 0.f; } // SW
            int col_z = e, col_y = EE + e;
            #pragma unroll
            for (int k = 0; k < 10; ++k) {
                int base = k * 1024 + tid4;
                v4f v = zero;
                #pragma unroll
                for (int j = 0; j < 4; ++j) {
                    if (base + j == col_z) v[j] = z;
                    if (base + j == col_y) v[j] = y;
                }
                nt_store(dst + base, v);
            }
        }
    }
}

extern "C" void kernel_launch(void* const* d_in, const int* in_sizes, int n_in,
                              void* d_out, int out_size, void* d_ws, size_t ws_size,
                              hipStream_t stream) {
    const float* M      = (const float*)d_in[0];   // f32, 2048x4096
    const float* params = (const float*)d_in[1];   // f32, 4096
    const int*   kinds  = (const int*)d_in[2];     // int32, 4096
    float*       out    = (float*)d_out;           // f32, 10240x10240

    coeff_kernel<<<TP_BLOCKS + TOT_ROWS, 256, 0, stream>>>(M, params, kinds, out);
}

// Round 7
// 426.074 us; speedup vs baseline: 1.0410x; 1.0073x over previous
//
#include <hip/hip_runtime.h>

// Inputs: M (f32, 2048x4096), params (f32, 4096), kinds (int32, 4096).
// Output: f32, 10240x10240.
// Timing model: fixed harness overhead ~343 us/iter (1.6 GiB ws poison 267 +
// 400 MiB out poison ~65 + input restore ~11). Controllable floor: 419 MB
// write + ~34 MB read @ 6.36 TB/s ~= 71 us -> window floor ~414 us.
// History: R3 437.6 / R4 434.2 / R5 443.5 / R6 429.2.
#define NN 2048              // N_NODES
#define EE 4096              // N_ELEMS
#define WW 10240             // 2*E + N columns
#define TOT_ROWS 10240       // N + 2*E rows

typedef float v4f __attribute__((ext_vector_type(4)));

#define TP_BLOCKS 512        // 512(M rows) x 32(M cols) tiles: 4 x 128

__device__ __forceinline__ void nt_store(float* p, v4f v) {
    __builtin_nontemporal_store(v, (v4f*)p);   // streamed, zero-reuse output
}

// Single fused kernel. Grid = [row blocks 0..10240) ++ [TP blocks ..+512).
//  Row blocks: one output ROW each, fully contiguous 32-40 KB stream:
//    rows [0,N):      [copy M row | zeros]  (copy chunk = 16 KB contiguous,
//                     up from 256 B in R6 — also warms M into L3 for TP)
//    rows [N,N+E):    [zeros | I_E]  cols [0,2E)  (-M^T owned by TP)
//    rows [N+E,2E+N): zeros + z@e + y@(E+e)
//  TP blocks (grid tail -> run last, M re-read is L3-resident):
//    512x32 tile of M -> -M^T rows [N,N+E), cols [2E,W); each output row
//    receives a 2 KB contiguous chunk (2x R6's 1 KB).
// Every output element is written exactly once (out re-poisoned each call).
__global__ __launch_bounds__(256) void coeff_kernel(
    const float* __restrict__ M,
    const float* __restrict__ params,
    const int*   __restrict__ kinds,
    float*       __restrict__ out)
{
    int tid = threadIdx.x;

    if (blockIdx.x < TOT_ROWS) {
        int row = blockIdx.x;
        int tid4 = tid * 4;
        float* dst = out + (size_t)row * WW;
        const v4f zero = {0.f, 0.f, 0.f, 0.f};

        if (row < NN) {
            // [copy M row | zeros] — one contiguous 40 KB stream
            const float* src = M + (size_t)row * EE;
            #pragma unroll
            for (int k = 0; k < 4; ++k) {
                int off = k * 1024 + tid4;
                nt_store(dst + off, *(const v4f*)(src + off));
            }
            #pragma unroll
            for (int k = 4; k < 10; ++k)
                nt_store(dst + k * 1024 + tid4, zero);
        } else if (row < NN + EE) {
            // [zeros | I_E] over cols [0,2E)
            int e = row - NN;
            int col_y = EE + e;
            #pragma unroll
            for (int k = 0; k < 8; ++k) {
                int base = k * 1024 + tid4;
                v4f v = zero;
                #pragma unroll
                for (int j = 0; j < 4; ++j)
                    if (base + j == col_y) v[j] = 1.0f;
                nt_store(dst + base, v);
            }
        } else {
            // elem rows: z at col e, y at col E+e
            int e = row - (NN + EE);
            float p = params[e];
            int kk = kinds[e];
            bool on = p > 0.0f;
            float z, y;
            if (kk == 0)      { z = -p;             y = 1.0f; }           // R
            else if (kk == 1) { z = 0.0f;           y = 1.0f; }           // IVS
            else if (kk == 2) { z = 1.0f;           y = 0.0f; }           // VC
            else              { z = on ? 0.f : 1.f; y = on ? 1.f : 0.f; } // SW
            int col_z = e, col_y = EE + e;
            #pragma unroll
            for (int k = 0; k < 10; ++k) {
                int base = k * 1024 + tid4;
                v4f v = zero;
                #pragma unroll
                for (int j = 0; j < 4; ++j) {
                    if (base + j == col_z) v[j] = z;
                    if (base + j == col_y) v[j] = y;
                }
                nt_store(dst + base, v);
            }
        }
    } else {
        // TP tile: 512 M-rows x 32 M-cols. LDS t[c][rr] with XOR swizzle
        // index c*512 + (rr ^ (c&28)):
        //  - write: 8 lanes sharing rr have distinct c&28 -> distinct banks;
        //    across a wave max 2-way aliasing (free per m136).
        //  - read: c fixed, (rr0+i)^(c&28) = (rr0^(c&28))+i for 4-aligned
        //    rr0 -> ds_read_b128 stays contiguous; uniform bank sweep.
        __shared__ __align__(16) float t[32 * 512];   // 64 KB
        int tpIdx = blockIdx.x - TOT_ROWS;            // [0, 512)
        int cT = (tpIdx & 127) << 5;   // M col base (output row base), 128 tiles
        int rT = (tpIdx >> 7) << 9;    // M row base (output col base), 4 tiles

        #pragma unroll
        for (int pass = 0; pass < 16; ++pass) {
            int rr = pass * 32 + (tid >> 3);          // M row within tile
            int c0 = (tid & 7) * 4;                   // M col within tile
            v4f val = *(const v4f*)(M + (size_t)(rT + rr) * EE + cT + c0);
            #pragma unroll
            for (int i = 0; i < 4; ++i) {
                int c = c0 + i;
                t[c * 512 + (rr ^ (c & 28))] = val[i];
            }
        }
        __syncthreads();

        #pragma unroll
        for (int pass = 0; pass < 16; ++pass) {
            int e   = pass * 2 + (tid >> 7);          // output row within tile
            int rr0 = (tid & 127) * 4;                // output col within tile
            v4f v = *(const v4f*)(&t[e * 512 + (rr0 ^ (e & 28))]);
            v4f nv = { -v[0], -v[1], -v[2], -v[3] };
            nt_store(out + (size_t)(NN + cT + e) * WW + 2 * EE + rT + rr0, nv);
        }
    }
}

extern "C" void kernel_launch(void* const* d_in, const int* in_sizes, int n_in,
                              void* d_out, int out_size, void* d_ws, size_t ws_size,
                              hipStream_t stream) {
    const float* M      = (const float*)d_in[0];   // f32, 2048x4096
    const float* params = (const float*)d_in[1];   // f32, 4096
    const int*   kinds  = (const int*)d_in[2];     // int32, 4096
    float*       out    = (float*)d_out;           // f32, 10240x10240

    coeff_kernel<<<TOT_ROWS + TP_BLOCKS, 256, 0, stream>>>(M, params, kinds, out);
}